// Round 1
// baseline (203.971 us; speedup 1.0000x reference)
//
#include <hip/hip_runtime.h>
#include <math.h>

#define B_DIM 4
#define N_DIM 8192
#define C_DIM 256
#define H_DIM 8
#define D_DIM 32
#define TM 64          // rows per block in K1
#define CH 16          // rows per register chunk
#define NCH (TM / CH)  // 4
#define RP 66          // padded row stride (floats) for transposed U tile
#define LN_EPS 1e-5f

// ---------------------------------------------------------------------------
// K1: per 64-row tile: Uk = U@Wk, Uv = U@Wv (f32 GEMM), LayerNorm(H*D) on each,
//     s[h] = <Wq[h,:], Uk_ln[h,:]>, partial qk[h,e] += s[h]*Uv_ln[h,e].
//     Thread t owns column t (t = h*32+d) of both Uk and Uv.
// ---------------------------------------------------------------------------
__global__ __launch_bounds__(256, 2)
void k1_gemm_ln_reduce(const float* __restrict__ U,
                       const float* __restrict__ Wq,
                       const float* __restrict__ Wk,
                       const float* __restrict__ Wv,
                       const float* __restrict__ gamma,
                       const float* __restrict__ beta,
                       float* __restrict__ part)   // [gridDim.x][256]
{
    __shared__ float Ut[C_DIM * RP];   // transposed tile: Ut[c*RP + r]
    __shared__ float red[4][CH][4];    // cross-wave stat partials

    const int t = threadIdx.x;
    const int bid = blockIdx.x;
    const int tiles_per_b = N_DIM / TM;           // 128
    const int b = bid / tiles_per_b;
    const int row0 = (bid % tiles_per_b) * TM;

    const float* __restrict__ Ub = U + ((size_t)b * N_DIM + row0) * C_DIM;

    // stage U tile transposed (coalesced global read, ~2-4 way LDS write conflict, negligible)
    for (int it = 0; it < TM; ++it) {
        Ut[t * RP + it] = Ub[(size_t)it * C_DIM + t];
    }
    __syncthreads();

    const int wave = t >> 6;
    const int lane = t & 63;

    const float wq = Wq[t];       // Wq flat [H*D] = [256]
    const float g  = gamma[t];
    const float be = beta[t];

    const float* __restrict__ wk_col = Wk + t;    // Wk[k*256 + t]
    const float* __restrict__ wv_col = Wv + t;

    float qk_acc = 0.f;

    for (int rc = 0; rc < NCH; ++rc) {
        const int r0 = rc * CH;
        float ak[CH], av[CH];
        #pragma unroll
        for (int i = 0; i < CH; ++i) { ak[i] = 0.f; av[i] = 0.f; }

        // GEMM inner loop: 2 weight loads + 16 broadcast LDS reads + 32 FMA per k
        #pragma unroll 2
        for (int k = 0; k < C_DIM; ++k) {
            const float wk = wk_col[(size_t)k * C_DIM];
            const float wv = wv_col[(size_t)k * C_DIM];
            const float* __restrict__ up = &Ut[k * RP + r0];
            #pragma unroll
            for (int i = 0; i < CH; ++i) {
                const float u = up[i];
                ak[i] = fmaf(u, wk, ak[i]);
                av[i] = fmaf(u, wv, av[i]);
            }
        }

        // per-row stats (sum, sumsq for k and v) across the 256 threads
        for (int r = 0; r < CH; ++r) {
            float s0 = ak[r], s1 = ak[r] * ak[r];
            float s2 = av[r], s3 = av[r] * av[r];
            #pragma unroll
            for (int m = 1; m <= 32; m <<= 1) {
                s0 += __shfl_xor(s0, m, 64);
                s1 += __shfl_xor(s1, m, 64);
                s2 += __shfl_xor(s2, m, 64);
                s3 += __shfl_xor(s3, m, 64);
            }
            if (lane == 0) {
                red[wave][r][0] = s0; red[wave][r][1] = s1;
                red[wave][r][2] = s2; red[wave][r][3] = s3;
            }
        }
        __syncthreads();

        for (int r = 0; r < CH; ++r) {
            const float sk  = red[0][r][0] + red[1][r][0] + red[2][r][0] + red[3][r][0];
            const float qkk = red[0][r][1] + red[1][r][1] + red[2][r][1] + red[3][r][1];
            const float sv  = red[0][r][2] + red[1][r][2] + red[2][r][2] + red[3][r][2];
            const float qvv = red[0][r][3] + red[1][r][3] + red[2][r][3] + red[3][r][3];

            const float muk  = sk * (1.f / 256.f);
            const float vark = qkk * (1.f / 256.f) - muk * muk;
            const float rsk  = 1.0f / sqrtf(vark + LN_EPS);
            const float muv  = sv * (1.f / 256.f);
            const float varv = qvv * (1.f / 256.f) - muv * muv;
            const float rsv  = 1.0f / sqrtf(varv + LN_EPS);

            const float lnk = (ak[r] - muk) * rsk * g + be;
            const float lnv = (av[r] - muv) * rsv * g + be;

            // s[h] = sum over the 32 lanes of this head group (t/32 = h)
            float p = wq * lnk;
            #pragma unroll
            for (int m = 1; m <= 16; m <<= 1) p += __shfl_xor(p, m, 64);

            qk_acc = fmaf(p, lnv, qk_acc);
        }
        __syncthreads();   // red reused next chunk
    }

    part[(size_t)bid * 256 + t] = qk_acc;
}

// ---------------------------------------------------------------------------
// K2: reduce 128 block-partials per batch -> qk[b][t]  (t = h*32+e)
// ---------------------------------------------------------------------------
__global__ void k2_reduce(const float* __restrict__ part, float* __restrict__ qk)
{
    const int b = blockIdx.x;
    const int t = threadIdx.x;
    const float* __restrict__ p = part + (size_t)b * 128 * 256 + t;
    float s = 0.f;
    for (int i = 0; i < 128; ++i) s += p[(size_t)i * 256];
    qk[b * 256 + t] = s;
}

// ---------------------------------------------------------------------------
// K3: out[b,n,e*H+h] = X[b,n] * qk[b,h*32+e] / N   (33.5 MB write, BW-bound)
// ---------------------------------------------------------------------------
__global__ __launch_bounds__(256)
void k3_out(const float* __restrict__ X, const float* __restrict__ qk,
            float* __restrict__ out)
{
    __shared__ float qkp[256];   // permuted + prescaled: qkp[e*8+h]
    const int t = threadIdx.x;
    const int bid = blockIdx.x;
    const int rows_per_block = 32;
    const int tiles_per_b = N_DIM / rows_per_block;   // 256
    const int b = bid / tiles_per_b;
    const int row0 = (bid % tiles_per_b) * rows_per_block;

    {
        const int h = t & 7;
        const int e = t >> 3;
        qkp[t] = qk[b * 256 + h * 32 + e] * (1.0f / (float)N_DIM);
    }
    __syncthreads();

    const int c4 = (t & 63) * 4;
    const float4 q4 = *(const float4*)&qkp[c4];
    const int rl = t >> 6;

    for (int it = 0; it < rows_per_block / 4; ++it) {
        const int row = row0 + it * 4 + rl;
        const float x = X[(size_t)b * N_DIM + row];
        float4 o;
        o.x = x * q4.x; o.y = x * q4.y; o.z = x * q4.z; o.w = x * q4.w;
        *(float4*)&out[((size_t)b * N_DIM + row) * C_DIM + c4] = o;
    }
}

// ---------------------------------------------------------------------------
extern "C" void kernel_launch(void* const* d_in, const int* in_sizes, int n_in,
                              void* d_out, int out_size, void* d_ws, size_t ws_size,
                              hipStream_t stream)
{
    const float* U     = (const float*)d_in[0];
    const float* X     = (const float*)d_in[1];
    const float* Wq    = (const float*)d_in[2];
    const float* Wk    = (const float*)d_in[3];
    const float* Wv    = (const float*)d_in[4];
    const float* gamma = (const float*)d_in[5];
    const float* beta  = (const float*)d_in[6];
    float* out = (float*)d_out;

    float* part = (float*)d_ws;                    // [512][256]
    float* qk   = part + 512 * 256;                // [4][256]

    const int n_tiles = B_DIM * (N_DIM / TM);      // 512
    k1_gemm_ln_reduce<<<n_tiles, 256, 0, stream>>>(U, Wq, Wk, Wv, gamma, beta, part);
    k2_reduce<<<B_DIM, 256, 0, stream>>>(part, qk);
    k3_out<<<B_DIM * (N_DIM / 32), 256, 0, stream>>>(X, qk, out);
}